// Round 10
// baseline (168.645 us; speedup 1.0000x reference)
//
#include <hip/hip_runtime.h>
#include <cstdint>
#include <cstddef>

#define KTOP 10
#define BQ 4096
#define BD 32768
#define THREADS 256
#define F4_PER_ROW (BD / 4)            // 8192
#define ITERS (F4_PER_ROW / THREADS)   // 32
#define WAVES 4
#define SLOTS 64                       // global candidate slots per wave (lambda ~11)
#define CAPG (WAVES * SLOTS)           // 256 per row
#define T_STATIC 3.0f
#define CAP_FUSED 2560                 // fused-fallback LDS cap

// ws layout: [0,16K) per_row float[BQ]; [16K,80K) counts int[BQ*WAVES];
//            [80K, +4M) gval float[BQ*CAPG]; then gidx int[BQ*CAPG].
#define WS_COUNTS 16384
#define WS_GVAL   (16384 + 65536)
#define WS_REQ ((size_t)WS_GVAL + (size_t)BQ * CAPG * 8)

// Exclusive prefix popcount of ballot mask below this lane (canonical mbcnt idiom).
__device__ __forceinline__ unsigned prefix_lt(unsigned long long b) {
    unsigned p = __builtin_amdgcn_mbcnt_lo((unsigned)(b & 0xffffffffull), 0u);
    return __builtin_amdgcn_mbcnt_hi((unsigned)(b >> 32), p);
}

// Tie-aware sorted top-10 register ladder insert (ties -> lower index, matches lax.top_k).
__device__ __forceinline__ void insert_tie(float v, int j, float (&tv)[KTOP], int (&ti)[KTOP]) {
    const bool enter = (v > tv[KTOP - 1]) || (v == tv[KTOP - 1] && j < ti[KTOP - 1]);
    if (enter) {
        bool cc[KTOP];
#pragma unroll
        for (int k = 0; k < KTOP; ++k) cc[k] = (v > tv[k]) || (v == tv[k] && j < ti[k]);
#pragma unroll
        for (int k = KTOP - 1; k >= 1; --k) {
            tv[k] = cc[k] ? (cc[k - 1] ? tv[k - 1] : v) : tv[k];
            ti[k] = cc[k] ? (cc[k - 1] ? ti[k - 1] : j) : ti[k];
        }
        if (cc[0]) { tv[0] = v; ti[0] = j; }
    }
}

// 10 wave-argmax extraction rounds over 64 lane-local ladders; no barriers.
__device__ __forceinline__ void wave_extract10(float (&tv)[KTOP], int (&ti)[KTOP],
                                               int lane, float &myv, int &myi) {
#pragma unroll
    for (int r = 0; r < KTOP; ++r) {
        float bv = tv[0]; int bi = ti[0]; int bl = lane;
#pragma unroll
        for (int m = 32; m >= 1; m >>= 1) {
            const float ov = __shfl_xor(bv, m);
            const int   oi = __shfl_xor(bi, m);
            const int   ol = __shfl_xor(bl, m);
            const bool take = (ov > bv) || (ov == bv && oi < bi);
            bv = take ? ov : bv;
            bi = take ? oi : bi;
            bl = take ? ol : bl;
        }
        if (lane == bl) {                       // winner pops its list head (static shift)
#pragma unroll
            for (int k = 0; k < KTOP - 1; ++k) { tv[k] = tv[k + 1]; ti[k] = ti[k + 1]; }
            tv[KTOP - 1] = -INFINITY; ti[KTOP - 1] = 0x7fffffff;
        }
        if (lane == r) { myv = bv; myi = bi; }
    }
}

// One wave owning one row: merged ladders -> top-10 -> NDCG loss.
__device__ __forceinline__ void wave_loss(float (&tv)[KTOP], int (&ti)[KTOP], int lane,
                                          const int* __restrict__ mrow, float* __restrict__ dst) {
    float myv = 0.0f; int myi = 0;
    wave_extract10(tv, ti, lane, myv, myi);
    const int pos = (lane < KTOP) ? ((mrow[myi] != 0) ? 1 : 0) : 0;
    int cnt = pos;
#pragma unroll
    for (int m = 32; m >= 1; m >>= 1) cnt += __shfl_xor(cnt, m);
    const float invd = 1.0f / log2f((float)(lane + 2));   // 1/log2(rank+1)
    float a = pos ? invd : 0.0f;
    float b = (lane < cnt) ? invd : 0.0f;
#pragma unroll
    for (int m = 32; m >= 1; m >>= 1) { a += __shfl_xor(a, m); b += __shfl_xor(b, m); }
    if (lane == 0) *dst = (b > 0.0f) ? (1.0f - a / b) : 0.0f;
}

// ---- Kernel A: one block per row. ATOMIC-FREE candidate collection: wave-level
// stream compaction via ballot + mbcnt prefix; wave-uniform count in register.
// No LDS, no barriers, fire-and-forget global stores; fully deterministic slots. ----
__global__ __launch_bounds__(THREADS) void collect_rows(
    const float* __restrict__ scores,
    float* __restrict__ gval, int* __restrict__ gidx, int* __restrict__ counts)
{
    const int row  = blockIdx.x;
    const int tid  = threadIdx.x;
    const int lane = tid & 63;
    const int wv   = tid >> 6;
    const float4* row4 = reinterpret_cast<const float4*>(scores + (size_t)row * BD);
    float* __restrict__ gv = gval + (size_t)row * CAPG + wv * SLOTS;
    int*   __restrict__ gi = gidx + (size_t)row * CAPG + wv * SLOTS;

    int cnt = 0;                               // wave-uniform (all lanes update identically)
    for (int i = 0; i < ITERS; ++i) {
        const int f4 = tid + i * THREADS;      // coalesced 64x16B per wave
        const float4 x = row4[f4];
        const float m = fmaxf(fmaxf(x.x, x.y), fmaxf(x.z, x.w));
        const unsigned long long any = __ballot(m >= T_STATIC);
        if (any) {                             // wave-uniform branch (~29% taken)
            const int jb = f4 * 4;
            const float vs[4] = { x.x, x.y, x.z, x.w };
#pragma unroll
            for (int c = 0; c < 4; ++c) {
                const bool cand = vs[c] >= T_STATIC;
                const unsigned long long b = __ballot(cand);
                if (b) {                       // wave-uniform
                    if (cand) {
                        const int slot = cnt + (int)prefix_lt(b);
                        if (slot < SLOTS) { gv[slot] = vs[c]; gi[slot] = jb + c; }
                    }
                    cnt += __popcll(b);        // uniform update, stays scalar
                }
            }
        }
    }
    if (lane == 0) counts[row * WAVES + wv] = cnt;
}

// ---- Kernel B: one wave per row; merge 4 wave-slices (or exact rescan) -> loss ----
__global__ __launch_bounds__(64) void merge_rows(
    const float* __restrict__ scores, const int* __restrict__ mask,
    const float* __restrict__ gval, const int* __restrict__ gidx,
    const int* __restrict__ counts, float* __restrict__ per_row)
{
    const int row  = blockIdx.x;
    const int lane = threadIdx.x;
    const int c0 = counts[row * WAVES + 0];
    const int c1 = counts[row * WAVES + 1];
    const int c2 = counts[row * WAVES + 2];
    const int c3 = counts[row * WAVES + 3];
    const bool ok = (c0 <= SLOTS) && (c1 <= SLOTS) && (c2 <= SLOTS) && (c3 <= SLOTS) &&
                    (c0 + c1 + c2 + c3 >= KTOP);

    float tv[KTOP]; int ti[KTOP];
#pragma unroll
    for (int k = 0; k < KTOP; ++k) { tv[k] = -INFINITY; ti[k] = 0x7fffffff; }

    if (ok) {
        const float* gv = gval + (size_t)row * CAPG;
        const int*   gi = gidx + (size_t)row * CAPG;
        const int cw[4] = { c0, c1, c2, c3 };
#pragma unroll
        for (int w = 0; w < 4; ++w)
            for (int p = lane; p < cw[w]; p += 64)
                insert_tie(gv[w * SLOTS + p], gi[w * SLOTS + p], tv, ti);
    } else {
        // Exact fallback for ANY input: wave rescans the full row (never taken for N(0,1)).
        const float4* row4 = reinterpret_cast<const float4*>(scores + (size_t)row * BD);
        for (int f4 = lane; f4 < F4_PER_ROW; f4 += 64) {
            const float4 x = row4[f4];
            const int jb = f4 * 4;
            const float vs[4] = { x.x, x.y, x.z, x.w };
#pragma unroll
            for (int c = 0; c < 4; ++c) insert_tie(vs[c], jb + c, tv, ti);
        }
    }
    wave_loss(tv, ti, lane, mask + (size_t)row * BD, per_row + row);
}

// ---- Fused fallback (round-3 structure) if ws is too small ----
__global__ __launch_bounds__(THREADS) void topk_ndcg_fused(
    const float* __restrict__ scores, const int* __restrict__ mask,
    float* __restrict__ per_row)
{
    const int row  = blockIdx.x;
    const int tid  = threadIdx.x;
    const int lane = tid & 63;
    const int wv   = tid >> 6;
    const float4* row4 = reinterpret_cast<const float4*>(scores + (size_t)row * BD);

    __shared__ int   s_cnt;
    __shared__ float cv[CAP_FUSED];
    __shared__ int   ci[CAP_FUSED];
    if (tid == 0) s_cnt = 0;
    __syncthreads();

    for (int i = 0; i < ITERS; ++i) {
        const int f4 = tid + i * THREADS;
        const float4 x = row4[f4];
        const float m = fmaxf(fmaxf(x.x, x.y), fmaxf(x.z, x.w));
        if (m >= T_STATIC) {
            const int jb = f4 * 4;
            const float vs[4] = { x.x, x.y, x.z, x.w };
#pragma unroll
            for (int c = 0; c < 4; ++c) {
                if (vs[c] >= T_STATIC) {
                    const int p = atomicAdd(&s_cnt, 1);
                    if (p < CAP_FUSED) { cv[p] = vs[c]; ci[p] = jb + c; }
                }
            }
        }
    }
    __syncthreads();
    int n = s_cnt;

    float tv[KTOP]; int ti[KTOP];
#pragma unroll
    for (int k = 0; k < KTOP; ++k) { tv[k] = -INFINITY; ti[k] = 0x7fffffff; }

    if (n < KTOP || n > CAP_FUSED) {
        for (int i = 0; i < ITERS; ++i) {
            const int f4 = i * THREADS + tid;
            const float4 x = row4[f4];
            const int jb = f4 * 4;
            const float vs[4] = { x.x, x.y, x.z, x.w };
#pragma unroll
            for (int c = 0; c < 4; ++c) insert_tie(vs[c], jb + c, tv, ti);
        }
        float fv = 0.0f; int fi = 0;
        wave_extract10(tv, ti, lane, fv, fi);
        if (lane < KTOP) { cv[wv * KTOP + lane] = fv; ci[wv * KTOP + lane] = fi; }
        __syncthreads();
        n = 4 * KTOP;
#pragma unroll
        for (int k = 0; k < KTOP; ++k) { tv[k] = -INFINITY; ti[k] = 0x7fffffff; }
    }

    if (wv == 0) {
        for (int p = lane; p < n; p += 64) insert_tie(cv[p], ci[p], tv, ti);
        wave_loss(tv, ti, lane, mask + (size_t)row * BD, per_row + row);
    }
}

// Deterministic reduction of the 4096 per-row losses -> scalar mean.
__global__ __launch_bounds__(256) void reduce_mean(
    const float* __restrict__ per_row, float* __restrict__ out)
{
    const int tid = threadIdx.x;
    float s = 0.0f;
    for (int i = tid; i < BQ; i += 256) s += per_row[i];
#pragma unroll
    for (int m = 32; m >= 1; m >>= 1) s += __shfl_xor(s, m);
    __shared__ float ws[4];
    if ((tid & 63) == 0) ws[tid >> 6] = s;
    __syncthreads();
    if (tid == 0) out[0] = (ws[0] + ws[1] + ws[2] + ws[3]) / (float)BQ;
}

extern "C" void kernel_launch(void* const* d_in, const int* in_sizes, int n_in,
                              void* d_out, int out_size, void* d_ws, size_t ws_size,
                              hipStream_t stream) {
    const float* scores = (const float*)d_in[0];
    const int*   mask   = (const int*)d_in[1];     // bool_ -> int32 on device

    char* ws = (char*)d_ws;
    float* per_row = (float*)ws;
    int*   counts  = (int*)(ws + WS_COUNTS);
    float* gval    = (float*)(ws + WS_GVAL);
    int*   gidx    = (int*)(ws + WS_GVAL + (size_t)BQ * CAPG * 4);

    if (ws_size >= WS_REQ) {
        collect_rows<<<BQ, THREADS, 0, stream>>>(scores, gval, gidx, counts);
        merge_rows<<<BQ, 64, 0, stream>>>(scores, mask, gval, gidx, counts, per_row);
    } else {
        topk_ndcg_fused<<<BQ, THREADS, 0, stream>>>(scores, mask, per_row);
    }
    reduce_mean<<<1, 256, 0, stream>>>(per_row, (float*)d_out);
}

// Round 11
// 137.676 us; speedup vs baseline: 1.2249x; 1.2249x over previous
//
#include <hip/hip_runtime.h>
#include <cstdint>
#include <cstddef>

#define KTOP 10
#define BQ 4096
#define BD 32768
#define THREADS 256
#define F4_PER_ROW (BD / 4)            // 8192
#define ITERS (F4_PER_ROW / THREADS)   // 32
#define CAPL 512                       // LDS collection slots (expected ~44/row)
#define CAPG 256                       // global candidate slots per row
#define T_STATIC 3.0f
#define QD 6                           // per-thread register queue depth (P(overflow)~1e-9)
#define CAP_FUSED 2560                 // fused-fallback LDS cap

// ws layout: [0,16K) per_row float[BQ]; [16K,32K) counts int[BQ];
//            [32K, +4M) gval float[BQ*CAPG]; then gidx int[BQ*CAPG].
#define WS_COUNTS 16384
#define WS_GVAL   32768
#define WS_REQ (WS_GVAL + (size_t)BQ * CAPG * 8)

// Tie-aware sorted top-10 register ladder insert (ties -> lower index, matches lax.top_k).
__device__ __forceinline__ void insert_tie(float v, int j, float (&tv)[KTOP], int (&ti)[KTOP]) {
    const bool enter = (v > tv[KTOP - 1]) || (v == tv[KTOP - 1] && j < ti[KTOP - 1]);
    if (enter) {
        bool cc[KTOP];
#pragma unroll
        for (int k = 0; k < KTOP; ++k) cc[k] = (v > tv[k]) || (v == tv[k] && j < ti[k]);
#pragma unroll
        for (int k = KTOP - 1; k >= 1; --k) {
            tv[k] = cc[k] ? (cc[k - 1] ? tv[k - 1] : v) : tv[k];
            ti[k] = cc[k] ? (cc[k - 1] ? ti[k - 1] : j) : ti[k];
        }
        if (cc[0]) { tv[0] = v; ti[0] = j; }
    }
}

// 10 wave-argmax extraction rounds over 64 lane-local ladders; no barriers.
__device__ __forceinline__ void wave_extract10(float (&tv)[KTOP], int (&ti)[KTOP],
                                               int lane, float &myv, int &myi) {
#pragma unroll
    for (int r = 0; r < KTOP; ++r) {
        float bv = tv[0]; int bi = ti[0]; int bl = lane;
#pragma unroll
        for (int m = 32; m >= 1; m >>= 1) {
            const float ov = __shfl_xor(bv, m);
            const int   oi = __shfl_xor(bi, m);
            const int   ol = __shfl_xor(bl, m);
            const bool take = (ov > bv) || (ov == bv && oi < bi);
            bv = take ? ov : bv;
            bi = take ? oi : bi;
            bl = take ? ol : bl;
        }
        if (lane == bl) {                       // winner pops its list head (static shift)
#pragma unroll
            for (int k = 0; k < KTOP - 1; ++k) { tv[k] = tv[k + 1]; ti[k] = ti[k + 1]; }
            tv[KTOP - 1] = -INFINITY; ti[KTOP - 1] = 0x7fffffff;
        }
        if (lane == r) { myv = bv; myi = bi; }
    }
}

// One wave owning one row: merged ladders -> top-10 -> NDCG loss.
__device__ __forceinline__ void wave_loss(float (&tv)[KTOP], int (&ti)[KTOP], int lane,
                                          const int* __restrict__ mrow, float* __restrict__ dst) {
    float myv = 0.0f; int myi = 0;
    wave_extract10(tv, ti, lane, myv, myi);
    const int pos = (lane < KTOP) ? ((mrow[myi] != 0) ? 1 : 0) : 0;
    int cnt = pos;
#pragma unroll
    for (int m = 32; m >= 1; m >>= 1) cnt += __shfl_xor(cnt, m);
    const float invd = 1.0f / log2f((float)(lane + 2));   // 1/log2(rank+1)
    float a = pos ? invd : 0.0f;
    float b = (lane < cnt) ? invd : 0.0f;
#pragma unroll
    for (int m = 32; m >= 1; m >>= 1) { a += __shfl_xor(a, m); b += __shfl_xor(b, m); }
    if (lane == 0) *dst = (b > 0.0f) ? (1.0f - a / b) : 0.0f;
}

// ---- Kernel A: one block per row (r7's winning shape). Hot loop has ZERO memory
// side ops: candidates bank into a 6-deep static-index register queue; one bulk
// LDS atomicAdd per candidate-holding thread AFTER the stream, then LDS->global dump.
__global__ __launch_bounds__(THREADS) void collect_rows(
    const float* __restrict__ scores,
    float* __restrict__ gval, int* __restrict__ gidx, int* __restrict__ counts)
{
    const int row = blockIdx.x;
    const int tid = threadIdx.x;
    const float4* row4 = reinterpret_cast<const float4*>(scores + (size_t)row * BD);

    __shared__ int   s_cnt;
    __shared__ float cv[CAPL];
    __shared__ int   ci[CAPL];
    if (tid == 0) s_cnt = 0;
    __syncthreads();

    float qv0 = 0, qv1 = 0, qv2 = 0, qv3 = 0, qv4 = 0, qv5 = 0;
    int   qj0 = 0, qj1 = 0, qj2 = 0, qj3 = 0, qj4 = 0, qj5 = 0;
    int   myn = 0;

    for (int i = 0; i < ITERS; ++i) {          // pure stream: load, max3, cmp
        const int f4 = tid + i * THREADS;
        const float4 x = row4[f4];
        const float m = fmaxf(fmaxf(x.x, x.y), fmaxf(x.z, x.w));
        if (m >= T_STATIC) {                   // ~29% of wave-iterations
            const int jb = f4 * 4;
            const float vs[4] = { x.x, x.y, x.z, x.w };
#pragma unroll
            for (int c = 0; c < 4; ++c) {
                if (vs[c] >= T_STATIC) {       // static-index register queue (rule #20)
                    const float v = vs[c]; const int j = jb + c;
                    if      (myn == 0) { qv0 = v; qj0 = j; }
                    else if (myn == 1) { qv1 = v; qj1 = j; }
                    else if (myn == 2) { qv2 = v; qj2 = j; }
                    else if (myn == 3) { qv3 = v; qj3 = j; }
                    else if (myn == 4) { qv4 = v; qj4 = j; }
                    else if (myn == 5) { qv5 = v; qj5 = j; }
                    ++myn;
                }
            }
        }
    }

    // Flush: one bulk slot allocation per thread-with-candidates.
    if (myn > 0) {
        const int add = (myn <= QD) ? myn : (CAPL + 1);   // overflow poisons the count
        const int p = atomicAdd(&s_cnt, add);
        if (myn <= QD) {
            if (p     < CAPL)            { cv[p]     = qv0; ci[p]     = qj0; }
            if (myn > 1 && p + 1 < CAPL) { cv[p + 1] = qv1; ci[p + 1] = qj1; }
            if (myn > 2 && p + 2 < CAPL) { cv[p + 2] = qv2; ci[p + 2] = qj2; }
            if (myn > 3 && p + 3 < CAPL) { cv[p + 3] = qv3; ci[p + 3] = qj3; }
            if (myn > 4 && p + 4 < CAPL) { cv[p + 4] = qv4; ci[p + 4] = qj4; }
            if (myn > 5 && p + 5 < CAPL) { cv[p + 5] = qv5; ci[p + 5] = qj5; }
        }
    }
    __syncthreads();
    const int n = s_cnt;                       // poisoned (>CAPG) on any overflow -> rescan
    const int nw = (n < CAPG) ? n : CAPG;
    for (int p = tid; p < nw; p += THREADS) {
        gval[(size_t)row * CAPG + p] = cv[p];
        gidx[(size_t)row * CAPG + p] = ci[p];
    }
    if (tid == 0) counts[row] = n;
}

// ---- Kernel B: one wave per row; merge candidates (or exact rescan) -> loss ----
__global__ __launch_bounds__(64) void merge_rows(
    const float* __restrict__ scores, const int* __restrict__ mask,
    const float* __restrict__ gval, const int* __restrict__ gidx,
    const int* __restrict__ counts, float* __restrict__ per_row)
{
    const int row  = blockIdx.x;
    const int lane = threadIdx.x;
    const int n = counts[row];

    float tv[KTOP]; int ti[KTOP];
#pragma unroll
    for (int k = 0; k < KTOP; ++k) { tv[k] = -INFINITY; ti[k] = 0x7fffffff; }

    if (n >= KTOP && n <= CAPG) {
        const float* gv = gval + (size_t)row * CAPG;
        const int*   gi = gidx + (size_t)row * CAPG;
        for (int p = lane; p < n; p += 64) insert_tie(gv[p], gi[p], tv, ti);
    } else {
        // Exact fallback for ANY input: wave rescans the full row.
        const float4* row4 = reinterpret_cast<const float4*>(scores + (size_t)row * BD);
        for (int f4 = lane; f4 < F4_PER_ROW; f4 += 64) {
            const float4 x = row4[f4];
            const int jb = f4 * 4;
            const float vs[4] = { x.x, x.y, x.z, x.w };
#pragma unroll
            for (int c = 0; c < 4; ++c) insert_tie(vs[c], jb + c, tv, ti);
        }
    }
    wave_loss(tv, ti, lane, mask + (size_t)row * BD, per_row + row);
}

// ---- Fused fallback (round-3 structure) if ws is too small ----
__global__ __launch_bounds__(THREADS) void topk_ndcg_fused(
    const float* __restrict__ scores, const int* __restrict__ mask,
    float* __restrict__ per_row)
{
    const int row  = blockIdx.x;
    const int tid  = threadIdx.x;
    const int lane = tid & 63;
    const int wv   = tid >> 6;
    const float4* row4 = reinterpret_cast<const float4*>(scores + (size_t)row * BD);

    __shared__ int   s_cnt;
    __shared__ float cv[CAP_FUSED];
    __shared__ int   ci[CAP_FUSED];
    if (tid == 0) s_cnt = 0;
    __syncthreads();

    for (int i = 0; i < ITERS; ++i) {
        const int f4 = tid + i * THREADS;
        const float4 x = row4[f4];
        const float m = fmaxf(fmaxf(x.x, x.y), fmaxf(x.z, x.w));
        if (m >= T_STATIC) {
            const int jb = f4 * 4;
            const float vs[4] = { x.x, x.y, x.z, x.w };
#pragma unroll
            for (int c = 0; c < 4; ++c) {
                if (vs[c] >= T_STATIC) {
                    const int p = atomicAdd(&s_cnt, 1);
                    if (p < CAP_FUSED) { cv[p] = vs[c]; ci[p] = jb + c; }
                }
            }
        }
    }
    __syncthreads();
    int n = s_cnt;

    float tv[KTOP]; int ti[KTOP];
#pragma unroll
    for (int k = 0; k < KTOP; ++k) { tv[k] = -INFINITY; ti[k] = 0x7fffffff; }

    if (n < KTOP || n > CAP_FUSED) {
        for (int i = 0; i < ITERS; ++i) {
            const int f4 = i * THREADS + tid;
            const float4 x = row4[f4];
            const int jb = f4 * 4;
            const float vs[4] = { x.x, x.y, x.z, x.w };
#pragma unroll
            for (int c = 0; c < 4; ++c) insert_tie(vs[c], jb + c, tv, ti);
        }
        float fv = 0.0f; int fi = 0;
        wave_extract10(tv, ti, lane, fv, fi);
        if (lane < KTOP) { cv[wv * KTOP + lane] = fv; ci[wv * KTOP + lane] = fi; }
        __syncthreads();
        n = 4 * KTOP;
#pragma unroll
        for (int k = 0; k < KTOP; ++k) { tv[k] = -INFINITY; ti[k] = 0x7fffffff; }
    }

    if (wv == 0) {
        for (int p = lane; p < n; p += 64) insert_tie(cv[p], ci[p], tv, ti);
        wave_loss(tv, ti, lane, mask + (size_t)row * BD, per_row + row);
    }
}

// Deterministic reduction of the 4096 per-row losses -> scalar mean.
__global__ __launch_bounds__(256) void reduce_mean(
    const float* __restrict__ per_row, float* __restrict__ out)
{
    const int tid = threadIdx.x;
    float s = 0.0f;
    for (int i = tid; i < BQ; i += 256) s += per_row[i];
#pragma unroll
    for (int m = 32; m >= 1; m >>= 1) s += __shfl_xor(s, m);
    __shared__ float ws[4];
    if ((tid & 63) == 0) ws[tid >> 6] = s;
    __syncthreads();
    if (tid == 0) out[0] = (ws[0] + ws[1] + ws[2] + ws[3]) / (float)BQ;
}

extern "C" void kernel_launch(void* const* d_in, const int* in_sizes, int n_in,
                              void* d_out, int out_size, void* d_ws, size_t ws_size,
                              hipStream_t stream) {
    const float* scores = (const float*)d_in[0];
    const int*   mask   = (const int*)d_in[1];     // bool_ -> int32 on device

    char* ws = (char*)d_ws;
    float* per_row = (float*)ws;
    int*   counts  = (int*)(ws + WS_COUNTS);
    float* gval    = (float*)(ws + WS_GVAL);
    int*   gidx    = (int*)(ws + WS_GVAL + (size_t)BQ * CAPG * 4);

    if (ws_size >= WS_REQ) {
        collect_rows<<<BQ, THREADS, 0, stream>>>(scores, gval, gidx, counts);
        merge_rows<<<BQ, 64, 0, stream>>>(scores, mask, gval, gidx, counts, per_row);
    } else {
        topk_ndcg_fused<<<BQ, THREADS, 0, stream>>>(scores, mask, per_row);
    }
    reduce_mean<<<1, 256, 0, stream>>>(per_row, (float*)d_out);
}